// Round 8
// baseline (306.150 us; speedup 1.0000x reference)
//
#include <hip/hip_runtime.h>
#include <hip/hip_bf16.h>
#include <math.h>

#define N_NODES  50000
#define N_EDGES  800000
#define IN_DIM   128
#define HID      256
#define FC1      1024
#define FC2      512
#define N_ACT    16
#define N_AGENTS 8192

#define BM 128
#define BN 128
#define BK 32
#define LDK 40   // padded LDS leading dim for the xw GEMM

typedef short bf16x8 __attribute__((ext_vector_type(8)));
typedef float floatx4 __attribute__((ext_vector_type(4)));

__device__ __forceinline__ unsigned short f2b(float f) {
    union { float f; unsigned int i; } v;
    v.f = f;
    unsigned int lsb = (v.i >> 16) & 1u;
    v.i += 0x7fffu + lsb;            // round-to-nearest-even
    return (unsigned short)(v.i >> 16);
}

__device__ __forceinline__ float b2f(unsigned short u) {
    union { unsigned int i; float f; } v;
    v.i = ((unsigned int)u) << 16;
    return v.f;
}

__device__ __forceinline__ bf16x8 pack8(float4 a, float4 b) {
    bf16x8 r;
    r[0] = (short)f2b(a.x); r[1] = (short)f2b(a.y);
    r[2] = (short)f2b(a.z); r[3] = (short)f2b(a.w);
    r[4] = (short)f2b(b.x); r[5] = (short)f2b(b.y);
    r[6] = (short)f2b(b.z); r[7] = (short)f2b(b.w);
    return r;
}

// ---- init: deg=0, mark=-1, fill=0, cnt=0, etot=0 ----
__global__ __launch_bounds__(256) void init_k(int* deg, int* nid, int* fill,
                                              int* cnt, int* etot) {
    int i = blockIdx.x * 256 + threadIdx.x;
    if (i < N_NODES) { deg[i] = 0; nid[i] = -1; }
    if (i < N_AGENTS) fill[i] = 0;
    if (i == 0) { *cnt = 0; *etot = 0; }
}

// ---- fused: claim marked nodes + in-degree over all edges ----
__global__ __launch_bounds__(256) void prep1_k(const int* __restrict__ agent_idx,
                                               int* __restrict__ nid,
                                               const int* __restrict__ dst,
                                               int* __restrict__ deg) {
    int i = blockIdx.x * 256 + threadIdx.x;
    if (i < N_AGENTS) atomicCAS(&nid[agent_idx[i]], -1, i);
    if (i < N_EDGES) atomicAdd(&deg[dst[i]], 1);
}

// ---- fused: compact ids + bump-alloc row bases + dis = rsqrt(deg+1) ----
__global__ __launch_bounds__(256) void prep2_k(int* __restrict__ nid,
                                               int* __restrict__ list,
                                               int* __restrict__ cnt,
                                               const int* __restrict__ deg,
                                               int* __restrict__ rowbeg,
                                               int* __restrict__ etot,
                                               float* __restrict__ dis) {
    int i = blockIdx.x * 256 + threadIdx.x;
    if (i < N_NODES) {
        int d = deg[i];
        dis[i] = rsqrtf((float)(d + 1));
        if (nid[i] != -1) {
            int c = atomicAdd(cnt, 1);
            nid[i] = c;
            list[c] = i;
            rowbeg[c] = atomicAdd(etot, d);
        }
    }
}

// ---- fill buckets: for needed dsts, append src to its row ----
__global__ __launch_bounds__(256) void fill_k(const int* __restrict__ src,
                                              const int* __restrict__ dst,
                                              const int* __restrict__ nid,
                                              const int* __restrict__ rowbeg,
                                              int* __restrict__ fill,
                                              int* __restrict__ ebuf) {
    int e = blockIdx.x * 256 + threadIdx.x;
    if (e >= N_EDGES) return;
    int c = nid[dst[e]];
    if (c < 0) return;
    int p = atomicAdd(&fill[c], 1);
    ebuf[rowbeg[c] + p] = src[e];
}

// ---- weight transpose+convert via LDS tiles: f32 [K,N] -> bf16 [N,K] ----
// 64x64 tiles; coalesced f32 reads AND coalesced 16B bf16 writes.
__global__ __launch_bounds__(256) void wtr_k(const float* __restrict__ Wgcn,
                                             const float* __restrict__ W1,
                                             const float* __restrict__ W2,
                                             const float* __restrict__ Wmu,
                                             unsigned short* __restrict__ wgcn_t,
                                             unsigned short* __restrict__ w1_t,
                                             unsigned short* __restrict__ w2_t,
                                             unsigned short* __restrict__ wmu_t) {
    __shared__ unsigned short Ts[64][72];
    int b = blockIdx.x;
    const float* src; unsigned short* dst; int K, N, tk, tn;
    if (b < 8)        { src = Wgcn; dst = wgcn_t; K = IN_DIM; N = HID;  tk = b >> 2;        tn = b & 3; }
    else if (b < 72)  { int bb = b - 8;  src = W1; dst = w1_t; K = HID;  N = FC1;  tk = bb >> 4; tn = bb & 15; }
    else if (b < 200) { int bb = b - 72; src = W2; dst = w2_t; K = FC1;  N = FC2;  tk = bb >> 3; tn = bb & 7; }
    else              { int bb = b - 200; src = Wmu; dst = wmu_t; K = FC2; N = N_ACT; tk = bb;   tn = 0; }
    int k0 = tk * 64, n0 = tn * 64;
    int tid = threadIdx.x;
    int r  = tid >> 2;
    int cc = (tid & 3) * 16;
    if (n0 + cc < N) {
        const float* p = src + (size_t)(k0 + r) * N + n0 + cc;
        #pragma unroll
        for (int i = 0; i < 16; i += 4) {
            float4 v = *(const float4*)(p + i);
            Ts[r][cc + i + 0] = f2b(v.x);
            Ts[r][cc + i + 1] = f2b(v.y);
            Ts[r][cc + i + 2] = f2b(v.z);
            Ts[r][cc + i + 3] = f2b(v.w);
        }
    }
    __syncthreads();
    int n = tid >> 2;
    if (n0 + n < N) {
        bf16x8 o0, o1;
        #pragma unroll
        for (int i = 0; i < 8; ++i) o0[i] = (short)Ts[cc + i][n];
        #pragma unroll
        for (int i = 0; i < 8; ++i) o1[i] = (short)Ts[cc + 8 + i][n];
        unsigned short* q = dst + (size_t)(n0 + n) * K + k0 + cc;
        *(bf16x8*)q = o0;
        *(bf16x8*)(q + 8) = o1;
    }
}

// ---- accumulate per needed node: sum in-edges + self-loop + bias, relu -> bf16 ----
__global__ __launch_bounds__(256) void accum_k(const int* __restrict__ cntp,
                                               const int* __restrict__ list,
                                               const int* __restrict__ rowbeg,
                                               const int* __restrict__ deg,
                                               const int* __restrict__ ebuf,
                                               const float* __restrict__ dis,
                                               const unsigned short* __restrict__ xw,
                                               const float* __restrict__ bgcn,
                                               unsigned short* __restrict__ h_node) {
    int c = blockIdx.x;
    if (c >= *cntp) return;
    int n = list[c];
    int lane = threadIdx.x & 63;
    int wave = threadIdx.x >> 6;
    int beg = rowbeg[c];
    int end = beg + deg[n];
    float dn = dis[n];
    floatx4 acc = {0.0f, 0.0f, 0.0f, 0.0f};
    for (int i = beg + wave; i < end; i += 4) {
        int s = ebuf[i];
        float w = dis[s] * dn;
        ushort4 u = *(const ushort4*)(xw + (size_t)s * HID + lane * 4);
        acc.x += w * b2f(u.x);
        acc.y += w * b2f(u.y);
        acc.z += w * b2f(u.z);
        acc.w += w * b2f(u.w);
    }
    __shared__ float part[4][HID];
    part[wave][lane * 4 + 0] = acc.x;
    part[wave][lane * 4 + 1] = acc.y;
    part[wave][lane * 4 + 2] = acc.z;
    part[wave][lane * 4 + 3] = acc.w;
    __syncthreads();
    int t = threadIdx.x;
    float v = part[0][t] + part[1][t] + part[2][t] + part[3][t];
    v += b2f(xw[(size_t)n * HID + t]) * dn * dn + bgcn[t];
    if (v < 0.0f) v = 0.0f;
    h_node[(size_t)c * HID + t] = f2b(v);
}

// ---- tiled GEMM with f32 A (converts during LDS staging): xw = x @ Wgcn ----
__global__ __launch_bounds__(256) void gemm_tiled_f32a_k(const float* __restrict__ A,
                                                         const unsigned short* __restrict__ Bt,
                                                         unsigned short* __restrict__ outb,
                                                         int M, int N, int K) {
    __shared__ unsigned short As[BM][LDK];
    __shared__ unsigned short Bs[BN][LDK];

    int tn = blockIdx.x;
    int tm = blockIdx.y;
    int tid = threadIdx.x;
    int lane = tid & 63;
    int wave = tid >> 6;
    int wm = wave >> 1, wn = wave & 1;
    int r16 = lane & 15, quad = lane >> 4;

    int srow = tid >> 2;
    int scol = (tid & 3) * 8;
    int ar0 = tm * BM + srow;        if (ar0 > M - 1) ar0 = M - 1;
    int ar1 = tm * BM + srow + 64;   if (ar1 > M - 1) ar1 = M - 1;
    int br0 = tn * BN + srow;
    int br1 = tn * BN + srow + 64;
    const float* pa0 = A + (size_t)ar0 * K + scol;
    const float* pa1 = A + (size_t)ar1 * K + scol;
    const unsigned short* pb0 = Bt + (size_t)br0 * K + scol;
    const unsigned short* pb1 = Bt + (size_t)br1 * K + scol;

    floatx4 acc[4][4];
    #pragma unroll
    for (int i = 0; i < 4; ++i)
        #pragma unroll
        for (int j = 0; j < 4; ++j)
            acc[i][j] = (floatx4){0.0f, 0.0f, 0.0f, 0.0f};

    float4 ra0a = *(const float4*)pa0, ra0b = *(const float4*)(pa0 + 4);
    float4 ra1a = *(const float4*)pa1, ra1b = *(const float4*)(pa1 + 4);
    bf16x8 rb0 = *(const bf16x8*)pb0;
    bf16x8 rb1 = *(const bf16x8*)pb1;

    for (int k0 = 0; k0 < K; k0 += BK) {
        *(bf16x8*)&As[srow][scol]      = pack8(ra0a, ra0b);
        *(bf16x8*)&As[srow + 64][scol] = pack8(ra1a, ra1b);
        *(bf16x8*)&Bs[srow][scol]      = rb0;
        *(bf16x8*)&Bs[srow + 64][scol] = rb1;
        __syncthreads();

        if (k0 + BK < K) {
            ra0a = *(const float4*)(pa0 + k0 + BK);
            ra0b = *(const float4*)(pa0 + k0 + BK + 4);
            ra1a = *(const float4*)(pa1 + k0 + BK);
            ra1b = *(const float4*)(pa1 + k0 + BK + 4);
            rb0 = *(const bf16x8*)(pb0 + k0 + BK);
            rb1 = *(const bf16x8*)(pb1 + k0 + BK);
        }

        bf16x8 af[4], bfr[4];
        #pragma unroll
        for (int i = 0; i < 4; ++i)
            af[i] = *(const bf16x8*)&As[wm * 64 + i * 16 + r16][quad * 8];
        #pragma unroll
        for (int j = 0; j < 4; ++j)
            bfr[j] = *(const bf16x8*)&Bs[wn * 64 + j * 16 + r16][quad * 8];
        #pragma unroll
        for (int i = 0; i < 4; ++i)
            #pragma unroll
            for (int j = 0; j < 4; ++j)
                acc[i][j] = __builtin_amdgcn_mfma_f32_16x16x32_bf16(af[i], bfr[j], acc[i][j], 0, 0, 0);
        __syncthreads();
    }

    #pragma unroll
    for (int j = 0; j < 4; ++j) {
        int ocol = tn * BN + wn * 64 + j * 16 + r16;
        #pragma unroll
        for (int i = 0; i < 4; ++i) {
            int orow_base = tm * BM + wm * 64 + i * 16 + quad * 4;
            #pragma unroll
            for (int r = 0; r < 4; ++r) {
                int orow = orow_base + r;
                if (orow < M)
                    outb[(size_t)orow * N + ocol] = f2b(acc[i][j][r]);
            }
        }
    }
}

// ---- fused FC1 + LayerNorm + ReLU, with agent-gather folded into A staging ----
// h1[a,:] = relu(LN(h_node[nid[agent[a]]] @ W1 + b1) * g1 + be1)
// BM=16 rows/block, full N=1024 in registers (acc 64 f32/thread), A K-resident in LDS.
__global__ __launch_bounds__(256) void fc1ln_k(const unsigned short* __restrict__ h_node,
                                               const int* __restrict__ agent,
                                               const int* __restrict__ nid,
                                               const unsigned short* __restrict__ w1t,
                                               const float* __restrict__ b1,
                                               const float* __restrict__ g1,
                                               const float* __restrict__ be1,
                                               unsigned short* __restrict__ h1) {
    __shared__ unsigned short As[16 * 264];        // 16 rows x K=256, stride 264
    __shared__ float sums[4][16][2];
    int tid = threadIdx.x, lane = tid & 63, wave = tid >> 6;
    int r16 = lane & 15, quad = lane >> 4;
    int tm = blockIdx.x;

    {   // stage A: 16 indirect rows x 256 bf16
        int row = tid >> 4;
        int c = nid[agent[tm * 16 + row]];
        const unsigned short* src = h_node + (size_t)c * HID;
        int kk = (tid & 15) * 8;
        *(bf16x8*)&As[row * 264 + kk]       = *(const bf16x8*)(src + kk);
        *(bf16x8*)&As[row * 264 + kk + 128] = *(const bf16x8*)(src + kk + 128);
    }
    __syncthreads();

    floatx4 acc[16];
    #pragma unroll
    for (int j = 0; j < 16; ++j) acc[j] = (floatx4){0.0f, 0.0f, 0.0f, 0.0f};
    float bias_r[16];
    #pragma unroll
    for (int j = 0; j < 16; ++j) bias_r[j] = b1[wave * 256 + j * 16 + r16];

    #pragma unroll
    for (int step = 0; step < 8; ++step) {
        bf16x8 a = *(const bf16x8*)&As[r16 * 264 + step * 32 + quad * 8];
        #pragma unroll
        for (int j = 0; j < 16; ++j) {
            int brow = wave * 256 + j * 16 + r16;
            bf16x8 b = *(const bf16x8*)(w1t + (size_t)brow * HID + step * 32 + quad * 8);
            acc[j] = __builtin_amdgcn_mfma_f32_16x16x32_bf16(a, b, acc[j], 0, 0, 0);
        }
    }

    float s[4] = {0, 0, 0, 0}, s2[4] = {0, 0, 0, 0};
    #pragma unroll
    for (int j = 0; j < 16; ++j)
        #pragma unroll
        for (int r = 0; r < 4; ++r) {
            float v = acc[j][r] + bias_r[j];
            s[r] += v; s2[r] += v * v;
        }
    #pragma unroll
    for (int m = 1; m < 16; m <<= 1)
        #pragma unroll
        for (int r = 0; r < 4; ++r) {
            s[r]  += __shfl_xor(s[r], m);
            s2[r] += __shfl_xor(s2[r], m);
        }
    if (r16 == 0)
        #pragma unroll
        for (int r = 0; r < 4; ++r) {
            sums[wave][quad * 4 + r][0] = s[r];
            sums[wave][quad * 4 + r][1] = s2[r];
        }
    __syncthreads();
    float mean[4], inv[4];
    #pragma unroll
    for (int r = 0; r < 4; ++r) {
        int row = quad * 4 + r;
        float S  = sums[0][row][0] + sums[1][row][0] + sums[2][row][0] + sums[3][row][0];
        float S2 = sums[0][row][1] + sums[1][row][1] + sums[2][row][1] + sums[3][row][1];
        mean[r] = S * (1.0f / FC1);
        float var = S2 * (1.0f / FC1) - mean[r] * mean[r];
        inv[r] = rsqrtf(var + 1e-5f);
    }
    #pragma unroll
    for (int j = 0; j < 16; ++j) {
        int cg = wave * 256 + j * 16 + r16;
        float gg = g1[cg], bb = be1[cg];
        #pragma unroll
        for (int r = 0; r < 4; ++r) {
            float v = (acc[j][r] + bias_r[j] - mean[r]) * inv[r] * gg + bb;
            if (v < 0.0f) v = 0.0f;
            h1[(size_t)(tm * 16 + quad * 4 + r) * FC1 + cg] = f2b(v);
        }
    }
}

// ---- fused FC2 + LayerNorm + ReLU + head (sigmoid(h2 @ Wmu + bmu)) ----
// BM=16 rows/block; h2 never touches global memory (LDS round-trip only).
__global__ __launch_bounds__(256) void fc2ln_head_k(const unsigned short* __restrict__ h1,
                                                    const unsigned short* __restrict__ w2t,
                                                    const float* __restrict__ b2,
                                                    const float* __restrict__ g2,
                                                    const float* __restrict__ be2,
                                                    const unsigned short* __restrict__ wmu_t,
                                                    const float* __restrict__ bmu,
                                                    float* __restrict__ out) {
    __shared__ unsigned short As[16 * 1032];       // A: 16 x K=1024; reused as h2 tile 16 x 520
    __shared__ float sums[4][16][2];
    __shared__ float hred[4][64][4];
    int tid = threadIdx.x, lane = tid & 63, wave = tid >> 6;
    int r16 = lane & 15, quad = lane >> 4;
    int tm = blockIdx.x;

    {   // stage A: 16 rows x 1024 bf16 from h1
        int row = tid >> 4;
        const unsigned short* src = h1 + (size_t)(tm * 16 + row) * FC1;
        #pragma unroll
        for (int it = 0; it < 8; ++it) {
            int kk = (tid & 15) * 8 + it * 128;
            *(bf16x8*)&As[row * 1032 + kk] = *(const bf16x8*)(src + kk);
        }
    }
    __syncthreads();

    floatx4 acc[8];
    #pragma unroll
    for (int j = 0; j < 8; ++j) acc[j] = (floatx4){0.0f, 0.0f, 0.0f, 0.0f};
    float bias_r[8];
    #pragma unroll
    for (int j = 0; j < 8; ++j) bias_r[j] = b2[wave * 128 + j * 16 + r16];

    for (int step = 0; step < 32; ++step) {
        bf16x8 a = *(const bf16x8*)&As[r16 * 1032 + step * 32 + quad * 8];
        #pragma unroll
        for (int j = 0; j < 8; ++j) {
            int brow = wave * 128 + j * 16 + r16;
            bf16x8 b = *(const bf16x8*)(w2t + (size_t)brow * FC1 + step * 32 + quad * 8);
            acc[j] = __builtin_amdgcn_mfma_f32_16x16x32_bf16(a, b, acc[j], 0, 0, 0);
        }
    }

    float s[4] = {0, 0, 0, 0}, s2[4] = {0, 0, 0, 0};
    #pragma unroll
    for (int j = 0; j < 8; ++j)
        #pragma unroll
        for (int r = 0; r < 4; ++r) {
            float v = acc[j][r] + bias_r[j];
            s[r] += v; s2[r] += v * v;
        }
    #pragma unroll
    for (int m = 1; m < 16; m <<= 1)
        #pragma unroll
        for (int r = 0; r < 4; ++r) {
            s[r]  += __shfl_xor(s[r], m);
            s2[r] += __shfl_xor(s2[r], m);
        }
    if (r16 == 0)
        #pragma unroll
        for (int r = 0; r < 4; ++r) {
            sums[wave][quad * 4 + r][0] = s[r];
            sums[wave][quad * 4 + r][1] = s2[r];
        }
    __syncthreads();    // also guarantees all waves are done reading As (K-loop)
    float mean[4], inv[4];
    #pragma unroll
    for (int r = 0; r < 4; ++r) {
        int row = quad * 4 + r;
        float S  = sums[0][row][0] + sums[1][row][0] + sums[2][row][0] + sums[3][row][0];
        float S2 = sums[0][row][1] + sums[1][row][1] + sums[2][row][1] + sums[3][row][1];
        mean[r] = S * (1.0f / FC2);
        float var = S2 * (1.0f / FC2) - mean[r] * mean[r];
        inv[r] = rsqrtf(var + 1e-5f);
    }
    // h2 tile (bf16) -> LDS (reuse As), stride 520
    #pragma unroll
    for (int j = 0; j < 8; ++j) {
        int cg = wave * 128 + j * 16 + r16;
        float gg = g2[cg], bb = be2[cg];
        #pragma unroll
        for (int r = 0; r < 4; ++r) {
            float v = (acc[j][r] + bias_r[j] - mean[r]) * inv[r] * gg + bb;
            if (v < 0.0f) v = 0.0f;
            As[(quad * 4 + r) * 520 + cg] = f2b(v);
        }
    }
    __syncthreads();
    // head: wave w covers K-slice [w*128, w*128+128)
    floatx4 hacc = {0.0f, 0.0f, 0.0f, 0.0f};
    #pragma unroll
    for (int st = 0; st < 4; ++st) {
        bf16x8 a = *(const bf16x8*)&As[r16 * 520 + wave * 128 + st * 32 + quad * 8];
        bf16x8 b = *(const bf16x8*)(wmu_t + (size_t)r16 * FC2 + wave * 128 + st * 32 + quad * 8);
        hacc = __builtin_amdgcn_mfma_f32_16x16x32_bf16(a, b, hacc, 0, 0, 0);
    }
    #pragma unroll
    for (int r = 0; r < 4; ++r) hred[wave][lane][r] = hacc[r];
    __syncthreads();
    if (wave == 0) {
        #pragma unroll
        for (int r = 0; r < 4; ++r) {
            float v = hred[0][lane][r] + hred[1][lane][r] + hred[2][lane][r] + hred[3][lane][r];
            v += bmu[r16];
            v = 1.0f / (1.0f + expf(-v));
            out[(size_t)(tm * 16 + quad * 4 + r) * N_ACT + r16] = v;
        }
    }
}

extern "C" void kernel_launch(void* const* d_in, const int* in_sizes, int n_in,
                              void* d_out, int out_size, void* d_ws, size_t ws_size,
                              hipStream_t stream) {
    const float* x    = (const float*)d_in[0];
    const int*   ei   = (const int*)d_in[1];
    const int*   agent= (const int*)d_in[2];
    const float* Wgcn = (const float*)d_in[3];
    const float* bgcn = (const float*)d_in[4];
    const float* W1   = (const float*)d_in[5];
    const float* b1   = (const float*)d_in[6];
    const float* g1   = (const float*)d_in[7];
    const float* be1  = (const float*)d_in[8];
    const float* W2   = (const float*)d_in[9];
    const float* b2   = (const float*)d_in[10];
    const float* g2   = (const float*)d_in[11];
    const float* be2  = (const float*)d_in[12];
    const float* Wmu  = (const float*)d_in[13];
    const float* bmu  = (const float*)d_in[14];
    float* out = (float*)d_out;

    const int* srcp = ei;
    const int* dstp = ei + N_EDGES;

    // workspace layout (256B aligned)
    char* ws = (char*)d_ws;
    size_t off = 0;
    int* deg = (int*)(ws + off);     off += ((size_t)N_NODES * 4 + 255) & ~(size_t)255;
    float* dis = (float*)(ws + off); off += ((size_t)N_NODES * 4 + 255) & ~(size_t)255;
    int* nid = (int*)(ws + off);     off += ((size_t)N_NODES * 4 + 255) & ~(size_t)255;
    int* list = (int*)(ws + off);    off += ((size_t)N_AGENTS * 4 + 255) & ~(size_t)255;
    int* cnt = (int*)(ws + off);     off += 256;
    int* etot = (int*)(ws + off);    off += 256;
    int* rowbeg = (int*)(ws + off);  off += ((size_t)N_AGENTS * 4 + 255) & ~(size_t)255;
    int* fill = (int*)(ws + off);    off += ((size_t)N_AGENTS * 4 + 255) & ~(size_t)255;
    int* ebuf = (int*)(ws + off);    off += ((size_t)N_EDGES * 4 + 255) & ~(size_t)255;
    unsigned short* wgcn_t = (unsigned short*)(ws + off); off += ((size_t)IN_DIM * HID * 2 + 255) & ~(size_t)255;
    unsigned short* w1_t   = (unsigned short*)(ws + off); off += ((size_t)HID * FC1 * 2 + 255) & ~(size_t)255;
    unsigned short* w2_t   = (unsigned short*)(ws + off); off += ((size_t)FC1 * FC2 * 2 + 255) & ~(size_t)255;
    unsigned short* wmu_t  = (unsigned short*)(ws + off); off += ((size_t)FC2 * N_ACT * 2 + 255) & ~(size_t)255;
    unsigned short* xw     = (unsigned short*)(ws + off); off += ((size_t)N_NODES * HID * 2 + 255) & ~(size_t)255;
    unsigned short* h_node = (unsigned short*)(ws + off); off += ((size_t)N_AGENTS * HID * 2 + 255) & ~(size_t)255;
    unsigned short* h1 = (unsigned short*)(ws + off);     off += ((size_t)N_AGENTS * FC1 * 2 + 255) & ~(size_t)255;

    // ---- graph prep / CSR build ----
    init_k<<<(N_NODES + 255) / 256, 256, 0, stream>>>(deg, nid, fill, cnt, etot);
    prep1_k<<<(N_EDGES + 255) / 256, 256, 0, stream>>>(agent, nid, dstp, deg);
    prep2_k<<<(N_NODES + 255) / 256, 256, 0, stream>>>(nid, list, cnt, deg, rowbeg, etot, dis);
    fill_k<<<(N_EDGES + 255) / 256, 256, 0, stream>>>(srcp, dstp, nid, rowbeg, fill, ebuf);

    // ---- weight transpose+convert (LDS tiles, coalesced both ways) ----
    wtr_k<<<208, 256, 0, stream>>>(Wgcn, W1, W2, Wmu, wgcn_t, w1_t, w2_t, wmu_t);

    // xw = x @ W_gcn (f32 A converted during staging)
    {
        dim3 grid(HID / BN, (N_NODES + BM - 1) / BM);
        gemm_tiled_f32a_k<<<grid, 256, 0, stream>>>(x, wgcn_t, xw, N_NODES, HID, IN_DIM);
    }

    // per-needed-node aggregation
    accum_k<<<N_AGENTS, 256, 0, stream>>>(cnt, list, rowbeg, deg, ebuf, dis, xw, bgcn, h_node);

    // FC1 + LN + ReLU (gather fused into A staging)
    fc1ln_k<<<N_AGENTS / 16, 256, 0, stream>>>(h_node, agent, nid, w1_t, b1, g1, be1, h1);

    // FC2 + LN + ReLU + head (h2 stays in LDS)
    fc2ln_head_k<<<N_AGENTS / 16, 256, 0, stream>>>(h1, w2_t, b2, g2, be2, wmu_t, bmu, out);
}

// Round 9
// 280.993 us; speedup vs baseline: 1.0895x; 1.0895x over previous
//
#include <hip/hip_runtime.h>
#include <hip/hip_bf16.h>
#include <math.h>

#define N_NODES  50000
#define N_EDGES  800000
#define IN_DIM   128
#define HID      256
#define FC1      1024
#define FC2      512
#define N_ACT    16
#define N_AGENTS 8192

#define BM 128
#define BN 128
#define BK 32
#define LDK 40   // padded LDS leading dim for tiled GEMMs

typedef short bf16x8 __attribute__((ext_vector_type(8)));
typedef float floatx4 __attribute__((ext_vector_type(4)));

__device__ __forceinline__ unsigned short f2b(float f) {
    union { float f; unsigned int i; } v;
    v.f = f;
    unsigned int lsb = (v.i >> 16) & 1u;
    v.i += 0x7fffu + lsb;            // round-to-nearest-even
    return (unsigned short)(v.i >> 16);
}

__device__ __forceinline__ float b2f(unsigned short u) {
    union { unsigned int i; float f; } v;
    v.i = ((unsigned int)u) << 16;
    return v.f;
}

__device__ __forceinline__ bf16x8 pack8(float4 a, float4 b) {
    bf16x8 r;
    r[0] = (short)f2b(a.x); r[1] = (short)f2b(a.y);
    r[2] = (short)f2b(a.z); r[3] = (short)f2b(a.w);
    r[4] = (short)f2b(b.x); r[5] = (short)f2b(b.y);
    r[6] = (short)f2b(b.z); r[7] = (short)f2b(b.w);
    return r;
}

// ---- init: deg=0, mark=-1, fill=0, cnt=0, etot=0 ----
__global__ __launch_bounds__(256) void init_k(int* deg, int* nid, int* fill,
                                              int* cnt, int* etot) {
    int i = blockIdx.x * 256 + threadIdx.x;
    if (i < N_NODES) { deg[i] = 0; nid[i] = -1; }
    if (i < N_AGENTS) fill[i] = 0;
    if (i == 0) { *cnt = 0; *etot = 0; }
}

// ---- fused: claim marked nodes + in-degree over all edges ----
__global__ __launch_bounds__(256) void prep1_k(const int* __restrict__ agent_idx,
                                               int* __restrict__ nid,
                                               const int* __restrict__ dst,
                                               int* __restrict__ deg) {
    int i = blockIdx.x * 256 + threadIdx.x;
    if (i < N_AGENTS) atomicCAS(&nid[agent_idx[i]], -1, i);
    if (i < N_EDGES) atomicAdd(&deg[dst[i]], 1);
}

// ---- fused: compact ids + bump-alloc row bases + dis = rsqrt(deg+1) ----
__global__ __launch_bounds__(256) void prep2_k(int* __restrict__ nid,
                                               int* __restrict__ list,
                                               int* __restrict__ cnt,
                                               const int* __restrict__ deg,
                                               int* __restrict__ rowbeg,
                                               int* __restrict__ etot,
                                               float* __restrict__ dis) {
    int i = blockIdx.x * 256 + threadIdx.x;
    if (i < N_NODES) {
        int d = deg[i];
        dis[i] = rsqrtf((float)(d + 1));
        if (nid[i] != -1) {
            int c = atomicAdd(cnt, 1);
            nid[i] = c;
            list[c] = i;
            rowbeg[c] = atomicAdd(etot, d);
        }
    }
}

// ---- fill buckets: for needed dsts, append src to its row ----
__global__ __launch_bounds__(256) void fill_k(const int* __restrict__ src,
                                              const int* __restrict__ dst,
                                              const int* __restrict__ nid,
                                              const int* __restrict__ rowbeg,
                                              int* __restrict__ fill,
                                              int* __restrict__ ebuf) {
    int e = blockIdx.x * 256 + threadIdx.x;
    if (e >= N_EDGES) return;
    int c = nid[dst[e]];
    if (c < 0) return;
    int p = atomicAdd(&fill[c], 1);
    ebuf[rowbeg[c] + p] = src[e];
}

// ---- weight transpose+convert via LDS tiles: f32 [K,N] -> bf16 [N,K] ----
// 64x64 tiles; coalesced f32 reads AND coalesced 16B bf16 writes. (validated R8)
__global__ __launch_bounds__(256) void wtr_k(const float* __restrict__ Wgcn,
                                             const float* __restrict__ W1,
                                             const float* __restrict__ W2,
                                             const float* __restrict__ Wmu,
                                             unsigned short* __restrict__ wgcn_t,
                                             unsigned short* __restrict__ w1_t,
                                             unsigned short* __restrict__ w2_t,
                                             unsigned short* __restrict__ wmu_t) {
    __shared__ unsigned short Ts[64][72];
    int b = blockIdx.x;
    const float* src; unsigned short* dst; int K, N, tk, tn;
    if (b < 8)        { src = Wgcn; dst = wgcn_t; K = IN_DIM; N = HID;  tk = b >> 2;        tn = b & 3; }
    else if (b < 72)  { int bb = b - 8;  src = W1; dst = w1_t; K = HID;  N = FC1;  tk = bb >> 4; tn = bb & 15; }
    else if (b < 200) { int bb = b - 72; src = W2; dst = w2_t; K = FC1;  N = FC2;  tk = bb >> 3; tn = bb & 7; }
    else              { int bb = b - 200; src = Wmu; dst = wmu_t; K = FC2; N = N_ACT; tk = bb;   tn = 0; }
    int k0 = tk * 64, n0 = tn * 64;
    int tid = threadIdx.x;
    int r  = tid >> 2;
    int cc = (tid & 3) * 16;
    if (n0 + cc < N) {
        const float* p = src + (size_t)(k0 + r) * N + n0 + cc;
        #pragma unroll
        for (int i = 0; i < 16; i += 4) {
            float4 v = *(const float4*)(p + i);
            Ts[r][cc + i + 0] = f2b(v.x);
            Ts[r][cc + i + 1] = f2b(v.y);
            Ts[r][cc + i + 2] = f2b(v.z);
            Ts[r][cc + i + 3] = f2b(v.w);
        }
    }
    __syncthreads();
    int n = tid >> 2;
    if (n0 + n < N) {
        bf16x8 o0, o1;
        #pragma unroll
        for (int i = 0; i < 8; ++i) o0[i] = (short)Ts[cc + i][n];
        #pragma unroll
        for (int i = 0; i < 8; ++i) o1[i] = (short)Ts[cc + 8 + i][n];
        unsigned short* q = dst + (size_t)(n0 + n) * K + k0 + cc;
        *(bf16x8*)q = o0;
        *(bf16x8*)(q + 8) = o1;
    }
}

// ---- accumulate per needed node: sum in-edges + self-loop + bias, relu -> bf16 ----
__global__ __launch_bounds__(256) void accum_k(const int* __restrict__ cntp,
                                               const int* __restrict__ list,
                                               const int* __restrict__ rowbeg,
                                               const int* __restrict__ deg,
                                               const int* __restrict__ ebuf,
                                               const float* __restrict__ dis,
                                               const unsigned short* __restrict__ xw,
                                               const float* __restrict__ bgcn,
                                               unsigned short* __restrict__ h_node) {
    int c = blockIdx.x;
    if (c >= *cntp) return;
    int n = list[c];
    int lane = threadIdx.x & 63;
    int wave = threadIdx.x >> 6;
    int beg = rowbeg[c];
    int end = beg + deg[n];
    float dn = dis[n];
    floatx4 acc = {0.0f, 0.0f, 0.0f, 0.0f};
    for (int i = beg + wave; i < end; i += 4) {
        int s = ebuf[i];
        float w = dis[s] * dn;
        ushort4 u = *(const ushort4*)(xw + (size_t)s * HID + lane * 4);
        acc.x += w * b2f(u.x);
        acc.y += w * b2f(u.y);
        acc.z += w * b2f(u.z);
        acc.w += w * b2f(u.w);
    }
    __shared__ float part[4][HID];
    part[wave][lane * 4 + 0] = acc.x;
    part[wave][lane * 4 + 1] = acc.y;
    part[wave][lane * 4 + 2] = acc.z;
    part[wave][lane * 4 + 3] = acc.w;
    __syncthreads();
    int t = threadIdx.x;
    float v = part[0][t] + part[1][t] + part[2][t] + part[3][t];
    v += b2f(xw[(size_t)n * HID + t]) * dn * dn + bgcn[t];
    if (v < 0.0f) v = 0.0f;
    h_node[(size_t)c * HID + t] = f2b(v);
}

// ---- gather per agent: copy its node's bf16 row ----
__global__ __launch_bounds__(256) void gather_k(const int* __restrict__ agent_idx,
                                                const int* __restrict__ nid,
                                                const unsigned short* __restrict__ h_node,
                                                unsigned short* __restrict__ h0) {
    int a = blockIdx.x;
    int t = threadIdx.x;
    int c = nid[agent_idx[a]];
    h0[(size_t)a * HID + t] = h_node[(size_t)c * HID + t];
}

// ---- tiled GEMM (bf16 A): C[M,N] = A[M,K] @ Bt[N,K]^T -> bf16 out ----
// mode 0: bf16(v); mode 1: bf16(v + bias)   (pre-LN values kept bf16: ~0.4% rel err, OK)
__global__ __launch_bounds__(256) void gemm_tiled_k(const unsigned short* __restrict__ A,
                                                    const unsigned short* __restrict__ Bt,
                                                    const float* __restrict__ bias,
                                                    unsigned short* __restrict__ outb,
                                                    int M, int N, int K, int mode) {
    __shared__ unsigned short As[BM][LDK];
    __shared__ unsigned short Bs[BN][LDK];

    int tn = blockIdx.x;
    int tm = blockIdx.y;
    int tid = threadIdx.x;
    int lane = tid & 63;
    int wave = tid >> 6;
    int wm = wave >> 1, wn = wave & 1;
    int r16 = lane & 15, quad = lane >> 4;

    int srow = tid >> 2;
    int scol = (tid & 3) * 8;
    int ar0 = tm * BM + srow;        if (ar0 > M - 1) ar0 = M - 1;
    int ar1 = tm * BM + srow + 64;   if (ar1 > M - 1) ar1 = M - 1;
    int br0 = tn * BN + srow;
    int br1 = tn * BN + srow + 64;
    const unsigned short* pa0 = A + (size_t)ar0 * K + scol;
    const unsigned short* pa1 = A + (size_t)ar1 * K + scol;
    const unsigned short* pb0 = Bt + (size_t)br0 * K + scol;
    const unsigned short* pb1 = Bt + (size_t)br1 * K + scol;

    floatx4 acc[4][4];
    #pragma unroll
    for (int i = 0; i < 4; ++i)
        #pragma unroll
        for (int j = 0; j < 4; ++j)
            acc[i][j] = (floatx4){0.0f, 0.0f, 0.0f, 0.0f};

    bf16x8 ra0 = *(const bf16x8*)pa0;
    bf16x8 ra1 = *(const bf16x8*)pa1;
    bf16x8 rb0 = *(const bf16x8*)pb0;
    bf16x8 rb1 = *(const bf16x8*)pb1;

    for (int k0 = 0; k0 < K; k0 += BK) {
        *(bf16x8*)&As[srow][scol]      = ra0;
        *(bf16x8*)&As[srow + 64][scol] = ra1;
        *(bf16x8*)&Bs[srow][scol]      = rb0;
        *(bf16x8*)&Bs[srow + 64][scol] = rb1;
        __syncthreads();

        if (k0 + BK < K) {
            ra0 = *(const bf16x8*)(pa0 + k0 + BK);
            ra1 = *(const bf16x8*)(pa1 + k0 + BK);
            rb0 = *(const bf16x8*)(pb0 + k0 + BK);
            rb1 = *(const bf16x8*)(pb1 + k0 + BK);
        }

        bf16x8 af[4], bfr[4];
        #pragma unroll
        for (int i = 0; i < 4; ++i)
            af[i] = *(const bf16x8*)&As[wm * 64 + i * 16 + r16][quad * 8];
        #pragma unroll
        for (int j = 0; j < 4; ++j)
            bfr[j] = *(const bf16x8*)&Bs[wn * 64 + j * 16 + r16][quad * 8];
        #pragma unroll
        for (int i = 0; i < 4; ++i)
            #pragma unroll
            for (int j = 0; j < 4; ++j)
                acc[i][j] = __builtin_amdgcn_mfma_f32_16x16x32_bf16(af[i], bfr[j], acc[i][j], 0, 0, 0);
        __syncthreads();
    }

    #pragma unroll
    for (int j = 0; j < 4; ++j) {
        int ocol = tn * BN + wn * 64 + j * 16 + r16;
        float bv = (mode != 0) ? bias[ocol] : 0.0f;
        #pragma unroll
        for (int i = 0; i < 4; ++i) {
            int orow_base = tm * BM + wm * 64 + i * 16 + quad * 4;
            #pragma unroll
            for (int r = 0; r < 4; ++r) {
                int orow = orow_base + r;
                if (orow < M)
                    outb[(size_t)orow * N + ocol] = f2b(acc[i][j][r] + bv);
            }
        }
    }
}

// ---- tiled GEMM with f32 A (converts during LDS staging): xw = x @ Wgcn ----
__global__ __launch_bounds__(256) void gemm_tiled_f32a_k(const float* __restrict__ A,
                                                         const unsigned short* __restrict__ Bt,
                                                         unsigned short* __restrict__ outb,
                                                         int M, int N, int K) {
    __shared__ unsigned short As[BM][LDK];
    __shared__ unsigned short Bs[BN][LDK];

    int tn = blockIdx.x;
    int tm = blockIdx.y;
    int tid = threadIdx.x;
    int lane = tid & 63;
    int wave = tid >> 6;
    int wm = wave >> 1, wn = wave & 1;
    int r16 = lane & 15, quad = lane >> 4;

    int srow = tid >> 2;
    int scol = (tid & 3) * 8;
    int ar0 = tm * BM + srow;        if (ar0 > M - 1) ar0 = M - 1;
    int ar1 = tm * BM + srow + 64;   if (ar1 > M - 1) ar1 = M - 1;
    int br0 = tn * BN + srow;
    int br1 = tn * BN + srow + 64;
    const float* pa0 = A + (size_t)ar0 * K + scol;
    const float* pa1 = A + (size_t)ar1 * K + scol;
    const unsigned short* pb0 = Bt + (size_t)br0 * K + scol;
    const unsigned short* pb1 = Bt + (size_t)br1 * K + scol;

    floatx4 acc[4][4];
    #pragma unroll
    for (int i = 0; i < 4; ++i)
        #pragma unroll
        for (int j = 0; j < 4; ++j)
            acc[i][j] = (floatx4){0.0f, 0.0f, 0.0f, 0.0f};

    float4 ra0a = *(const float4*)pa0, ra0b = *(const float4*)(pa0 + 4);
    float4 ra1a = *(const float4*)pa1, ra1b = *(const float4*)(pa1 + 4);
    bf16x8 rb0 = *(const bf16x8*)pb0;
    bf16x8 rb1 = *(const bf16x8*)pb1;

    for (int k0 = 0; k0 < K; k0 += BK) {
        *(bf16x8*)&As[srow][scol]      = pack8(ra0a, ra0b);
        *(bf16x8*)&As[srow + 64][scol] = pack8(ra1a, ra1b);
        *(bf16x8*)&Bs[srow][scol]      = rb0;
        *(bf16x8*)&Bs[srow + 64][scol] = rb1;
        __syncthreads();

        if (k0 + BK < K) {
            ra0a = *(const float4*)(pa0 + k0 + BK);
            ra0b = *(const float4*)(pa0 + k0 + BK + 4);
            ra1a = *(const float4*)(pa1 + k0 + BK);
            ra1b = *(const float4*)(pa1 + k0 + BK + 4);
            rb0 = *(const bf16x8*)(pb0 + k0 + BK);
            rb1 = *(const bf16x8*)(pb1 + k0 + BK);
        }

        bf16x8 af[4], bfr[4];
        #pragma unroll
        for (int i = 0; i < 4; ++i)
            af[i] = *(const bf16x8*)&As[wm * 64 + i * 16 + r16][quad * 8];
        #pragma unroll
        for (int j = 0; j < 4; ++j)
            bfr[j] = *(const bf16x8*)&Bs[wn * 64 + j * 16 + r16][quad * 8];
        #pragma unroll
        for (int i = 0; i < 4; ++i)
            #pragma unroll
            for (int j = 0; j < 4; ++j)
                acc[i][j] = __builtin_amdgcn_mfma_f32_16x16x32_bf16(af[i], bfr[j], acc[i][j], 0, 0, 0);
        __syncthreads();
    }

    #pragma unroll
    for (int j = 0; j < 4; ++j) {
        int ocol = tn * BN + wn * 64 + j * 16 + r16;
        #pragma unroll
        for (int i = 0; i < 4; ++i) {
            int orow_base = tm * BM + wm * 64 + i * 16 + quad * 4;
            #pragma unroll
            for (int r = 0; r < 4; ++r) {
                int orow = orow_base + r;
                if (orow < M)
                    outb[(size_t)orow * N + ocol] = f2b(acc[i][j][r]);
            }
        }
    }
}

// ---- head: out = sigmoid(h2[8192,512] @ wmu_t[16,512]^T + bmu), K split over 4 waves ----
__global__ __launch_bounds__(256) void head_k(const unsigned short* __restrict__ h2,
                                              const unsigned short* __restrict__ wmu_t,
                                              const float* __restrict__ bmu,
                                              float* __restrict__ out) {
    int blk = blockIdx.x;                 // 512 blocks x 16 rows
    int lane = threadIdx.x & 63;
    int wave = threadIdx.x >> 6;
    int r16 = lane & 15, quad = lane >> 4;
    int row0 = blk * 16;
    const bf16x8* pa = (const bf16x8*)(h2 + (size_t)(row0 + r16) * FC2 + wave * 128 + quad * 8);
    const bf16x8* pb = (const bf16x8*)(wmu_t + (size_t)r16 * FC2 + wave * 128 + quad * 8);
    floatx4 acc = {0.0f, 0.0f, 0.0f, 0.0f};
    #pragma unroll
    for (int s = 0; s < 4; ++s)
        acc = __builtin_amdgcn_mfma_f32_16x16x32_bf16(pa[4 * s], pb[4 * s], acc, 0, 0, 0);
    __shared__ float part[4][64][4];
    #pragma unroll
    for (int r = 0; r < 4; ++r) part[wave][lane][r] = acc[r];
    __syncthreads();
    if (wave == 0) {
        #pragma unroll
        for (int r = 0; r < 4; ++r) {
            float v = part[0][lane][r] + part[1][lane][r] + part[2][lane][r] + part[3][lane][r];
            v += bmu[r16];
            v = 1.0f / (1.0f + expf(-v));
            out[(size_t)(row0 + quad * 4 + r) * N_ACT + r16] = v;
        }
    }
}

// ---- single-pass row LayerNorm (+affine) + relu, bf16 in -> bf16 out ----
__global__ __launch_bounds__(256) void ln_relu_k(const unsigned short* __restrict__ z,
                                                 const float* __restrict__ g,
                                                 const float* __restrict__ be,
                                                 unsigned short* __restrict__ out, int L) {
    size_t base = (size_t)blockIdx.x * L;
    int nc = L >> 8;                 // 4 (FC1) or 2 (FC2)
    float vreg[4];
    float s = 0.0f, s2 = 0.0f;
    for (int i = 0; i < nc; ++i) {
        float v = b2f(z[base + i * 256 + threadIdx.x]);
        vreg[i] = v;
        s += v;
        s2 += v * v;
    }
    for (int off = 32; off > 0; off >>= 1) {
        s += __shfl_down(s, off);
        s2 += __shfl_down(s2, off);
    }
    __shared__ float red[8];
    int wave = threadIdx.x >> 6;
    int lane = threadIdx.x & 63;
    if (lane == 0) { red[wave] = s; red[4 + wave] = s2; }
    __syncthreads();
    s  = red[0] + red[1] + red[2] + red[3];
    s2 = red[4] + red[5] + red[6] + red[7];
    float invL = 1.0f / (float)L;
    float mean = s * invL;
    float var = s2 * invL - mean * mean;
    float inv = rsqrtf(var + 1e-5f);
    for (int i = 0; i < nc; ++i) {
        int c = i * 256 + threadIdx.x;
        float v = (vreg[i] - mean) * inv * g[c] + be[c];
        if (v < 0.0f) v = 0.0f;
        out[base + c] = f2b(v);
    }
}

extern "C" void kernel_launch(void* const* d_in, const int* in_sizes, int n_in,
                              void* d_out, int out_size, void* d_ws, size_t ws_size,
                              hipStream_t stream) {
    const float* x    = (const float*)d_in[0];
    const int*   ei   = (const int*)d_in[1];
    const int*   agent= (const int*)d_in[2];
    const float* Wgcn = (const float*)d_in[3];
    const float* bgcn = (const float*)d_in[4];
    const float* W1   = (const float*)d_in[5];
    const float* b1   = (const float*)d_in[6];
    const float* g1   = (const float*)d_in[7];
    const float* be1  = (const float*)d_in[8];
    const float* W2   = (const float*)d_in[9];
    const float* b2   = (const float*)d_in[10];
    const float* g2   = (const float*)d_in[11];
    const float* be2  = (const float*)d_in[12];
    const float* Wmu  = (const float*)d_in[13];
    const float* bmu  = (const float*)d_in[14];
    float* out = (float*)d_out;

    const int* srcp = ei;
    const int* dstp = ei + N_EDGES;

    // workspace layout (256B aligned)
    char* ws = (char*)d_ws;
    size_t off = 0;
    int* deg = (int*)(ws + off);     off += ((size_t)N_NODES * 4 + 255) & ~(size_t)255;
    float* dis = (float*)(ws + off); off += ((size_t)N_NODES * 4 + 255) & ~(size_t)255;
    int* nid = (int*)(ws + off);     off += ((size_t)N_NODES * 4 + 255) & ~(size_t)255;
    int* list = (int*)(ws + off);    off += ((size_t)N_AGENTS * 4 + 255) & ~(size_t)255;
    int* cnt = (int*)(ws + off);     off += 256;
    int* etot = (int*)(ws + off);    off += 256;
    int* rowbeg = (int*)(ws + off);  off += ((size_t)N_AGENTS * 4 + 255) & ~(size_t)255;
    int* fill = (int*)(ws + off);    off += ((size_t)N_AGENTS * 4 + 255) & ~(size_t)255;
    int* ebuf = (int*)(ws + off);    off += ((size_t)N_EDGES * 4 + 255) & ~(size_t)255;
    unsigned short* wgcn_t = (unsigned short*)(ws + off); off += ((size_t)IN_DIM * HID * 2 + 255) & ~(size_t)255;
    unsigned short* w1_t   = (unsigned short*)(ws + off); off += ((size_t)HID * FC1 * 2 + 255) & ~(size_t)255;
    unsigned short* w2_t   = (unsigned short*)(ws + off); off += ((size_t)FC1 * FC2 * 2 + 255) & ~(size_t)255;
    unsigned short* wmu_t  = (unsigned short*)(ws + off); off += ((size_t)FC2 * N_ACT * 2 + 255) & ~(size_t)255;
    unsigned short* xw     = (unsigned short*)(ws + off); off += ((size_t)N_NODES * HID * 2 + 255) & ~(size_t)255;
    unsigned short* h_node = (unsigned short*)(ws + off); off += ((size_t)N_AGENTS * HID * 2 + 255) & ~(size_t)255;
    unsigned short* h0 = (unsigned short*)(ws + off);     off += ((size_t)N_AGENTS * HID * 2 + 255) & ~(size_t)255;
    unsigned short* zb = (unsigned short*)(ws + off);     off += ((size_t)N_AGENTS * FC1 * 2 + 255) & ~(size_t)255;
    unsigned short* h1 = (unsigned short*)(ws + off);     off += ((size_t)N_AGENTS * FC1 * 2 + 255) & ~(size_t)255;
    unsigned short* h2 = (unsigned short*)(ws + off);     off += ((size_t)N_AGENTS * FC2 * 2 + 255) & ~(size_t)255;

    // ---- graph prep / CSR build ----
    init_k<<<(N_NODES + 255) / 256, 256, 0, stream>>>(deg, nid, fill, cnt, etot);
    prep1_k<<<(N_EDGES + 255) / 256, 256, 0, stream>>>(agent, nid, dstp, deg);
    prep2_k<<<(N_NODES + 255) / 256, 256, 0, stream>>>(nid, list, cnt, deg, rowbeg, etot, dis);
    fill_k<<<(N_EDGES + 255) / 256, 256, 0, stream>>>(srcp, dstp, nid, rowbeg, fill, ebuf);

    // ---- weight transpose+convert (LDS tiles, coalesced both ways) ----
    wtr_k<<<208, 256, 0, stream>>>(Wgcn, W1, W2, Wmu, wgcn_t, w1_t, w2_t, wmu_t);

    // xw = x @ W_gcn (f32 A converted during staging)
    {
        dim3 grid(HID / BN, (N_NODES + BM - 1) / BM);
        gemm_tiled_f32a_k<<<grid, 256, 0, stream>>>(x, wgcn_t, xw, N_NODES, HID, IN_DIM);
    }

    // per-needed-node aggregation
    accum_k<<<N_AGENTS, 256, 0, stream>>>(cnt, list, rowbeg, deg, ebuf, dis, xw, bgcn, h_node);

    // per-agent gather
    gather_k<<<N_AGENTS, 256, 0, stream>>>(agent, nid, h_node, h0);

    // FC1 -> LN+relu
    {
        dim3 grid(FC1 / BN, N_AGENTS / BM);
        gemm_tiled_k<<<grid, 256, 0, stream>>>(h0, w1_t, b1, zb, N_AGENTS, FC1, HID, 1);
        ln_relu_k<<<N_AGENTS, 256, 0, stream>>>(zb, g1, be1, h1, FC1);
    }

    // FC2 -> LN+relu
    {
        dim3 grid(FC2 / BN, N_AGENTS / BM);
        gemm_tiled_k<<<grid, 256, 0, stream>>>(h1, w2_t, b2, zb, N_AGENTS, FC2, FC1, 1);
        ln_relu_k<<<N_AGENTS, 256, 0, stream>>>(zb, g2, be2, h2, FC2);
    }

    // head: sigmoid(h2 @ Wmu + bmu), K split over waves
    head_k<<<N_AGENTS / 16, 256, 0, stream>>>(h2, wmu_t, bmu, out);
}